// Round 8
// baseline (64.570 us; speedup 1.0000x reference)
//
#include <hip/hip_runtime.h>
#include <math.h>

constexpr int B = 8, C = 21, H = 512, W = 512;
constexpr int HW = H * W;
constexpr int THREADS = 64;                           // 1 wave per block
constexpr int PPL = 4;                                // pixels per lane (float4)
constexpr int PIX_PER_TILE = THREADS * PPL;           // 256
constexpr int NITER = 16;                             // tiles per block
constexpr int PIX_PER_BLOCK = PIX_PER_TILE * NITER;   // 4096
constexpr int BLOCKS_PER_BATCH = HW / PIX_PER_BLOCK;  // 64
constexpr int NBLOCKS = B * BLOCKS_PER_BATCH;         // 512 = 2 per CU exactly

// ws layout (floats)
constexpr int WS_PSUM = 0;                  // B*C
constexpr int WS_INTER = B * C;
constexpr int WS_TSUM = 2 * B * C;
constexpr int WS_CE = 3 * B * C;            // NBLOCKS
constexpr int WS_FOC = 3 * B * C + NBLOCKS;

typedef __attribute__((address_space(3))) unsigned lds_u32;
typedef const __attribute__((address_space(1))) unsigned g_u32;

__global__ __launch_bounds__(THREADS) void combo_main(
        const float* __restrict__ pred, const int* __restrict__ tgt,
        float* __restrict__ ws) {
    __shared__ float tile[2][C][PIX_PER_TILE];   // 2 x 21 KB
    __shared__ int tgt_t[2][PIX_PER_TILE];       // 2 x 1 KB
    __shared__ float s_inter[C], s_tsum[C];

    const int lane = threadIdx.x;
    if (lane < C) { s_inter[lane] = 0.0f; s_tsum[lane] = 0.0f; }

    const int bid = blockIdx.x;
    const int b = bid / BLOCKS_PER_BATCH;
    const int chunk = bid - b * BLOCKS_PER_BATCH;

    // per-lane global bases (16 B per lane per op)
    const float* gpred =
        pred + (size_t)b * C * HW + (size_t)chunk * PIX_PER_BLOCK + lane * PPL;
    const int* gtgt =
        tgt + (size_t)b * HW + (size_t)chunk * PIX_PER_BLOCK + lane * PPL;

    float r[C];
#pragma unroll
    for (int c = 0; c < C; ++c) r[c] = 0.0f;
    float ce_acc = 0.0f, foc_acc = 0.0f;

    // ---- issue tile t: 21 fat class ops (1 KB each) + 1 target op ----
    auto issue = [&](int t) {
        const int buf = t & 1;
        const float* g = gpred + t * PIX_PER_TILE;
#pragma unroll
        for (int c = 0; c < C; ++c) {
            __builtin_amdgcn_global_load_lds((g_u32*)(g + (size_t)c * HW),
                                             (lds_u32*)&tile[buf][c][0], 16, 0, 0);
        }
        __builtin_amdgcn_global_load_lds((g_u32*)(gtgt + t * PIX_PER_TILE),
                                         (lds_u32*)&tgt_t[buf][0], 16, 0, 0);
    };

    issue(0);
    for (int t = 0; t < NITER; ++t) {
        if (t + 1 < NITER) {
            issue(t + 1);
            // tile t landed; tile t+1's 22 ops stay in flight
            asm volatile("s_waitcnt vmcnt(22)" ::: "memory");
        } else {
            asm volatile("s_waitcnt vmcnt(0)" ::: "memory");
        }
        __builtin_amdgcn_sched_barrier(0);

        const int buf = t & 1;
        const int4 tg = *(const int4*)&tgt_t[buf][lane * PPL];

        // ---- pass 1: exp, per-pixel sums, capture x[target]; e stays in regs ----
        float e[C][PPL];                      // 84 VGPRs
        float4 s4 = make_float4(0.f, 0.f, 0.f, 0.f);
        float4 xt = make_float4(0.f, 0.f, 0.f, 0.f);
#pragma unroll
        for (int c = 0; c < C; ++c) {
            float4 x = *(const float4*)&tile[buf][c][lane * PPL];
            float e0 = __expf(x.x), e1 = __expf(x.y);
            float e2 = __expf(x.z), e3 = __expf(x.w);
            e[c][0] = e0; e[c][1] = e1; e[c][2] = e2; e[c][3] = e3;
            s4.x += e0; s4.y += e1; s4.z += e2; s4.w += e3;
            xt.x = (tg.x == c) ? x.x : xt.x;
            xt.y = (tg.y == c) ? x.y : xt.y;
            xt.z = (tg.z == c) ? x.z : xt.z;
            xt.w = (tg.w == c) ? x.w : xt.w;
        }

        float4 lns;
        lns.x = __logf(s4.x); lns.y = __logf(s4.y);
        lns.z = __logf(s4.z); lns.w = __logf(s4.w);

        float ce0 = lns.x - xt.x, ce1 = lns.y - xt.y;
        float ce2 = lns.z - xt.z, ce3 = lns.w - xt.w;
        float pt0 = __expf(-ce0), pt1 = __expf(-ce1);
        float pt2 = __expf(-ce2), pt3 = __expf(-ce3);
        float om0 = 1.f - pt0, om1 = 1.f - pt1, om2 = 1.f - pt2, om3 = 1.f - pt3;
        ce_acc += ce0 + ce1 + ce2 + ce3;
        foc_acc += om0 * om0 * ce0 + om1 * om1 * ce1 +
                   om2 * om2 * ce2 + om3 * om3 * ce3;

        atomicAdd(&s_inter[tg.x], pt0);
        atomicAdd(&s_inter[tg.y], pt1);
        atomicAdd(&s_inter[tg.z], pt2);
        atomicAdd(&s_inter[tg.w], pt3);
        atomicAdd(&s_tsum[tg.x], 1.0f);
        atomicAdd(&s_tsum[tg.y], 1.0f);
        atomicAdd(&s_tsum[tg.z], 1.0f);
        atomicAdd(&s_tsum[tg.w], 1.0f);

        // ---- pass 2: per-class prob partials, pure registers ----
        float4 inv;
        inv.x = __builtin_amdgcn_rcpf(s4.x);
        inv.y = __builtin_amdgcn_rcpf(s4.y);
        inv.z = __builtin_amdgcn_rcpf(s4.z);
        inv.w = __builtin_amdgcn_rcpf(s4.w);
#pragma unroll
        for (int c = 0; c < C; ++c) {
            r[c] += e[c][0] * inv.x + e[c][1] * inv.y +
                    e[c][2] * inv.z + e[c][3] * inv.w;
        }
    }

    // ---- wave butterfly reductions; lane c keeps class-c total ----
    float rmine = 0.0f;
#pragma unroll
    for (int c = 0; c < C; ++c) {
        float v = r[c];
#pragma unroll
        for (int o = 32; o; o >>= 1) v += __shfl_xor(v, o, 64);
        rmine = (lane == c) ? v : rmine;
    }
#pragma unroll
    for (int o = 32; o; o >>= 1) {
        ce_acc += __shfl_xor(ce_acc, o, 64);
        foc_acc += __shfl_xor(foc_acc, o, 64);
    }

    if (lane < C) {
        atomicAdd(&ws[WS_PSUM + b * C + lane], rmine);
        atomicAdd(&ws[WS_INTER + b * C + lane], s_inter[lane]);
        atomicAdd(&ws[WS_TSUM + b * C + lane], s_tsum[lane]);
    }
    if (lane == 0) {
        ws[WS_CE + bid] = ce_acc;
        ws[WS_FOC + bid] = foc_acc;
    }
}

__global__ __launch_bounds__(256) void combo_final(
        const float* __restrict__ ws, float* __restrict__ out) {
    __shared__ float s_ce, s_foc, s_dj, s_jj;
    if (threadIdx.x == 0) { s_ce = 0.f; s_foc = 0.f; s_dj = 0.f; s_jj = 0.f; }
    __syncthreads();

    const int tid = threadIdx.x;
    float ce = 0.f, fo = 0.f;
    for (int i = tid; i < NBLOCKS; i += 256) {
        ce += ws[WS_CE + i];
        fo += ws[WS_FOC + i];
    }
    float dj = 0.f, jj = 0.f;
    for (int i = tid; i < B * C; i += 256) {
        float it = ws[WS_INTER + i], ps = ws[WS_PSUM + i], ts = ws[WS_TSUM + i];
        dj += (2.0f * it + 1.0f) / (ps + ts + 1.0f);
        jj += (it + 1.0f) / (ps + ts - it + 1.0f);
    }
    const int lane = tid & 63;
#pragma unroll
    for (int o = 32; o; o >>= 1) {
        ce += __shfl_xor(ce, o, 64);
        fo += __shfl_xor(fo, o, 64);
        dj += __shfl_xor(dj, o, 64);
        jj += __shfl_xor(jj, o, 64);
    }
    if (lane == 0) {
        atomicAdd(&s_ce, ce);
        atomicAdd(&s_foc, fo);
        atomicAdd(&s_dj, dj);
        atomicAdd(&s_jj, jj);
    }
    __syncthreads();
    if (tid == 0) {
        const float N = (float)B * (float)HW;
        out[0] = s_ce / N + s_foc / N +
                 (1.0f - s_dj / (float)(B * C)) +
                 (1.0f - s_jj / (float)(B * C));
    }
}

extern "C" void kernel_launch(void* const* d_in, const int* in_sizes, int n_in,
                              void* d_out, int out_size, void* d_ws, size_t ws_size,
                              hipStream_t stream) {
    const float* pred = (const float*)d_in[0];
    const int* tgt = (const int*)d_in[1];
    float* ws = (float*)d_ws;
    float* out = (float*)d_out;

    hipMemsetAsync(ws, 0, 3 * B * C * sizeof(float), stream);
    combo_main<<<NBLOCKS, THREADS, 0, stream>>>(pred, tgt, ws);
    combo_final<<<1, 256, 0, stream>>>(ws, out);
}